// Round 1
// baseline (17868.767 us; speedup 1.0000x reference)
//
#include <hip/hip_runtime.h>
#include <stdint.h>

#define Bv 64
#define Tv 2048
#define Iv 128
#define Hv 512
#define Ov 64

typedef _Float16 half_t;
typedef _Float16 half2_t __attribute__((ext_vector_type(2)));

__device__ __forceinline__ float fdot2(unsigned int a, unsigned int b, float c) {
#if __has_builtin(__builtin_amdgcn_fdot2)
    return __builtin_amdgcn_fdot2(__builtin_bit_cast(half2_t, a),
                                  __builtin_bit_cast(half2_t, b), c, false);
#else
    half2_t ha = __builtin_bit_cast(half2_t, a);
    half2_t hb = __builtin_bit_cast(half2_t, b);
    return c + (float)ha.x * (float)hb.x + (float)ha.y * (float)hb.y;
#endif
}

// ---- weight pre-pack kernels (run once per launch; trivial cost) ----
// wrecp[q][j][k] (q<64, j<512, k<4), uint = half2(wrec[j][8q+2k], wrec[j][8q+2k+1])
__global__ void pack_wrec_k(const float* __restrict__ wrec, unsigned int* __restrict__ wp) {
    int tid = blockIdx.x * 256 + threadIdx.x;            // < 131072
    int k = tid & 3, j = (tid >> 2) & 511, q = tid >> 11;
    int i0 = 8 * q + 2 * k;
    half2_t v;
    v.x = (half_t)wrec[j * Hv + i0];
    v.y = (half_t)wrec[j * Hv + i0 + 1];
    wp[tid] = __builtin_bit_cast(unsigned int, v);
}

// wip[q][j][k] (q<16), uint = half2(wi[8q+2k][j], wi[8q+2k+1][j])
__global__ void pack_wi_k(const float* __restrict__ wi, unsigned int* __restrict__ wp) {
    int tid = blockIdx.x * 256 + threadIdx.x;            // < 32768
    int k = tid & 3, j = (tid >> 2) & 511, q = tid >> 11;
    int i0 = 8 * q + 2 * k;
    half2_t v;
    v.x = (half_t)wi[i0 * Hv + j];
    v.y = (half_t)wi[(i0 + 1) * Hv + j];
    wp[tid] = __builtin_bit_cast(unsigned int, v);
}

// wop[m][o] (m<256, o<64), uint = half2(wout[2m][o], wout[2m+1][o])
__global__ void pack_wout_k(const float* __restrict__ wout, unsigned int* __restrict__ wp) {
    int tid = blockIdx.x * 256 + threadIdx.x;            // < 16384
    int o = tid & 63, m = tid >> 6;
    half2_t v;
    v.x = (half_t)wout[(2 * m) * Ov + o];
    v.y = (half_t)wout[(2 * m + 1) * Ov + o];
    wp[tid] = __builtin_bit_cast(unsigned int, v);
}

// ---- persistent RNN kernel: 1 workgroup per batch, 512 threads ----
__global__ __launch_bounds__(512) void rnn_persistent(
    const float* __restrict__ x, const float* __restrict__ noise,
    const float* __restrict__ h0,
    const unsigned int* __restrict__ wrecp,
    const unsigned int* __restrict__ wip,
    const unsigned int* __restrict__ wop,
    float* __restrict__ out)
{
    __shared__ __align__(16) unsigned int s_r[2][256]; // half2-packed tanh(h), ping-pong
    __shared__ __align__(16) unsigned int s_x[64];     // half2-packed x[t]

    const int tid = threadIdx.x;     // owns h column tid
    const int b = blockIdx.x;
    const int o = tid >> 3;          // output column for wout phase
    const int g = tid & 7;           // 8-way split of the 512-dot for wout

    const float* xb = x + (size_t)b * Tv * Iv;
    const float* nb = noise + (size_t)b * Tv * Hv;
    float* ob = out + (size_t)b * Tv * Ov;

    // register-resident wi column (thread tid): 64 uints = 128 f16
    unsigned int wiReg[64];
#pragma unroll
    for (int m = 0; m < 64; ++m)
        wiReg[m] = wip[(((m >> 2) * Hv) + tid) * 4 + (m & 3)];

    // register-resident wout slice for (o, g): 32 uints = 64 f16
    unsigned int wo[32];
#pragma unroll
    for (int k = 0; k < 32; ++k)
        wo[k] = wop[(g * 32 + k) * Ov + o];

    float h = h0[tid];
    ((half_t*)&s_r[0][0])[tid] = (half_t)tanhf(h);
    __syncthreads();

    // out[:,0,:] = tanh(h0) @ wout
    {
        float po = 0.f;
        const uint4* r2 = (const uint4*)&s_r[0][0];
#pragma unroll
        for (int k = 0; k < 8; ++k) {
            uint4 rv = r2[g * 8 + k];
            po = fdot2(wo[4 * k + 0], rv.x, po);
            po = fdot2(wo[4 * k + 1], rv.y, po);
            po = fdot2(wo[4 * k + 2], rv.z, po);
            po = fdot2(wo[4 * k + 3], rv.w, po);
        }
        po += __shfl_xor(po, 1, 64);
        po += __shfl_xor(po, 2, 64);
        po += __shfl_xor(po, 4, 64);
        if (g == 0) ob[o] = po;
    }

    const uint4* wr4 = (const uint4*)wrecp;
    int cur = 0;
    for (int t = 0; t < Tv - 1; ++t) {
        const int nxt = cur ^ 1;

        // (a) stage inputs for this step
        float nval = nb[t * Hv + tid];
        if (tid < Iv) ((half_t*)&s_x[0])[tid] = (half_t)xb[t * Iv + tid];
        __syncthreads();                                   // (b) s_x ready, s_r[cur] ready

        // (c) acc = (r @ wrec.T)[tid] + (x @ wi)[tid]
        float acc = 0.f;
        const uint4* rr4 = (const uint4*)&s_r[cur][0];
#pragma unroll 8
        for (int q = 0; q < 64; ++q) {
            uint4 w = wr4[q * Hv + tid];   // coalesced 16B/lane from L2-resident packed wrec
            uint4 r = rr4[q];              // LDS broadcast
            acc = fdot2(w.x, r.x, acc);
            acc = fdot2(w.y, r.y, acc);
            acc = fdot2(w.z, r.z, acc);
            acc = fdot2(w.w, r.w, acc);
        }
        const uint4* xx4 = (const uint4*)&s_x[0];
#pragma unroll
        for (int m = 0; m < 16; ++m) {
            uint4 xv = xx4[m];
            acc = fdot2(wiReg[4 * m + 0], xv.x, acc);
            acc = fdot2(wiReg[4 * m + 1], xv.y, acc);
            acc = fdot2(wiReg[4 * m + 2], xv.z, acc);
            acc = fdot2(wiReg[4 * m + 3], xv.w, acc);
        }

        // (d) state update (f32), publish r_{t+1} = tanh(h) as f16
        h = h + 0.0005f * nval + 0.1f * (acc - h);
        ((half_t*)&s_r[nxt][0])[tid] = (half_t)tanhf(h);
        __syncthreads();                                   // (e) s_r[nxt] ready

        // (f) out[b][t+1][:] = tanh(h_{t+1}) @ wout
        float po = 0.f;
        const uint4* r2 = (const uint4*)&s_r[nxt][0];
#pragma unroll
        for (int k = 0; k < 8; ++k) {
            uint4 rv = r2[g * 8 + k];
            po = fdot2(wo[4 * k + 0], rv.x, po);
            po = fdot2(wo[4 * k + 1], rv.y, po);
            po = fdot2(wo[4 * k + 2], rv.z, po);
            po = fdot2(wo[4 * k + 3], rv.w, po);
        }
        po += __shfl_xor(po, 1, 64);
        po += __shfl_xor(po, 2, 64);
        po += __shfl_xor(po, 4, 64);
        if (g == 0) ob[(t + 1) * Ov + o] = po;

        cur = nxt;
    }
}

extern "C" void kernel_launch(void* const* d_in, const int* in_sizes, int n_in,
                              void* d_out, int out_size, void* d_ws, size_t ws_size,
                              hipStream_t stream) {
    const float* input = (const float*)d_in[0];
    const float* noise = (const float*)d_in[1];
    const float* wi    = (const float*)d_in[2];
    const float* wrec  = (const float*)d_in[3];
    const float* wout  = (const float*)d_in[4];
    const float* h0    = (const float*)d_in[5];
    float* out = (float*)d_out;

    // ws layout (f16-packed weights): wrec 512KB | wi 128KB | wout 64KB  (704KB total)
    unsigned int* wrecp = (unsigned int*)d_ws;
    unsigned int* wip   = wrecp + 64 * 512 * 4;   // +131072 uints
    unsigned int* wop   = wip   + 16 * 512 * 4;   // +32768 uints

    hipLaunchKernelGGL(pack_wrec_k, dim3(512), dim3(256), 0, stream, wrec, wrecp);
    hipLaunchKernelGGL(pack_wi_k,   dim3(128), dim3(256), 0, stream, wi, wip);
    hipLaunchKernelGGL(pack_wout_k, dim3(64),  dim3(256), 0, stream, wout, wop);
    hipLaunchKernelGGL(rnn_persistent, dim3(Bv), dim3(512), 0, stream,
                       input, noise, h0, wrecp, wip, wop, out);
}

// Round 2
// 3584.376 us; speedup vs baseline: 4.9852x; 4.9852x over previous
//
#include <hip/hip_runtime.h>
#include <stdint.h>

#define Bv 64
#define Tv 2048
#define Iv 128
#define Hv 512
#define Ov 64

typedef _Float16 half_t;
typedef _Float16 half2_t __attribute__((ext_vector_type(2)));

__device__ __forceinline__ float fdot2(unsigned int a, unsigned int b, float c) {
#if __has_builtin(__builtin_amdgcn_fdot2)
    return __builtin_amdgcn_fdot2(__builtin_bit_cast(half2_t, a),
                                  __builtin_bit_cast(half2_t, b), c, false);
#else
    half2_t ha = __builtin_bit_cast(half2_t, a);
    half2_t hb = __builtin_bit_cast(half2_t, b);
    return c + (float)ha.x * (float)hb.x + (float)ha.y * (float)hb.y;
#endif
}

__device__ __forceinline__ unsigned int pack2(float a, float b) {
    half2_t v; v.x = (half_t)a; v.y = (half_t)b;
    return __builtin_bit_cast(unsigned int, v);
}

// ===================== FAST PATH =====================
// Split of wrec row k-range: [0,360) -> registers (180 uints), [360,512) -> LDS (76 uints = 19 uint4)

// wrA[m][j] (m<180, j<512): half2(wrec[j][2m], wrec[j][2m+1])
__global__ void pack_wrA_k(const float* __restrict__ wrec, unsigned int* __restrict__ wp) {
    int idx = blockIdx.x * 256 + threadIdx.x;           // < 92160
    if (idx >= 180 * 512) return;
    int j = idx & 511, m = idx >> 9;
    wp[idx] = pack2(wrec[j * Hv + 2 * m], wrec[j * Hv + 2 * m + 1]);
}

// wB[g][j][c] (g<19, j<512, c<4): half2(wrec[j][360+8g+2c], wrec[j][360+8g+2c+1])
__global__ void pack_wB_k(const float* __restrict__ wrec, unsigned int* __restrict__ wp) {
    int idx = blockIdx.x * 256 + threadIdx.x;           // < 38912
    if (idx >= 19 * 512 * 4) return;
    int c = idx & 3, j = (idx >> 2) & 511, g = idx >> 11;
    int k = 360 + 8 * g + 2 * c;
    wp[idx] = pack2(wrec[j * Hv + k], wrec[j * Hv + k + 1]);
}

// wip[m][j] (m<64, j<512): half2(wi[2m][j], wi[2m+1][j])
__global__ void pack_wip_k(const float* __restrict__ wi, unsigned int* __restrict__ wp) {
    int idx = blockIdx.x * 256 + threadIdx.x;           // < 32768
    int j = idx & 511, m = idx >> 9;
    wp[idx] = pack2(wi[(2 * m) * Hv + j], wi[(2 * m + 1) * Hv + j]);
}

// wop4[g][o] (g<64, o<64): uint4 of half2(wout[8g+2c][o], wout[8g+2c+1][o]) c<4
__global__ void pack_wop_k(const float* __restrict__ wout, uint4* __restrict__ wp) {
    int idx = blockIdx.x * 256 + threadIdx.x;           // < 4096
    if (idx >= 64 * 64) return;
    int o = idx & 63, g = idx >> 6;
    uint4 v;
    v.x = pack2(wout[(8 * g + 0) * Ov + o], wout[(8 * g + 1) * Ov + o]);
    v.y = pack2(wout[(8 * g + 2) * Ov + o], wout[(8 * g + 3) * Ov + o]);
    v.z = pack2(wout[(8 * g + 4) * Ov + o], wout[(8 * g + 5) * Ov + o]);
    v.w = pack2(wout[(8 * g + 6) * Ov + o], wout[(8 * g + 7) * Ov + o]);
    wp[idx] = v;
}

// z[bt][j] = 0.1 * sum_i x[bt][i]*wi[i][j] + 0.0005 * noise[bt][j], f16. 32 bt-rows/block.
__global__ __launch_bounds__(512) void z_kernel(
    const float* __restrict__ x, const float* __restrict__ noise,
    const unsigned int* __restrict__ wip, half_t* __restrict__ zg)
{
    __shared__ uint4 xs[32 * 16];   // [row][g], 8 KB
    const int tid = threadIdx.x;
    const size_t bt0 = (size_t)blockIdx.x * 32;

    unsigned int wiR[64];
#pragma unroll
    for (int m = 0; m < 64; ++m) wiR[m] = wip[m * 512 + tid];

    for (int idx = tid; idx < 32 * 64; idx += 512) {
        int row = idx >> 6, m = idx & 63;
        float2 xv = ((const float2*)x)[(bt0 + row) * 64 + m];
        ((unsigned int*)xs)[idx] = pack2(xv.x, xv.y);
    }
    __syncthreads();

    for (int row = 0; row < 32; ++row) {
        float a0 = 0.f, a1 = 0.f, a2 = 0.f, a3 = 0.f;
#pragma unroll
        for (int g = 0; g < 16; ++g) {
            uint4 xv = xs[row * 16 + g];
            a0 = fdot2(wiR[4 * g + 0], xv.x, a0);
            a1 = fdot2(wiR[4 * g + 1], xv.y, a1);
            a2 = fdot2(wiR[4 * g + 2], xv.z, a2);
            a3 = fdot2(wiR[4 * g + 3], xv.w, a3);
        }
        float nv = noise[(bt0 + row) * 512 + tid];
        zg[(bt0 + row) * 512 + tid] = (half_t)(0.1f * ((a0 + a1) + (a2 + a3)) + 0.0005f * nv);
    }
}

// Persistent scan: 1 WG/batch, 512 threads, wrec in regs+LDS, r published via LDS ping-pong.
__global__ __launch_bounds__(512, 2) void rnn_fast(
    const unsigned int* __restrict__ wrAg,   // [180][512]
    const uint4* __restrict__ wBg,           // [19][512]
    const half_t* __restrict__ zg,           // [B][T][512]
    const float* __restrict__ h0,
    half_t* __restrict__ rstore)             // [B][T][512]
{
    extern __shared__ unsigned char smem[];
    uint4* wlds = (uint4*)smem;                                   // 19*512*16 = 155648 B
    half_t* s_r16 = (half_t*)(smem + 19 * 512 * 16);              // [2][512] f16 = 2048 B
    const uint4* s_r4 = (const uint4*)s_r16;

    const int tid = threadIdx.x;
    const int b = blockIdx.x;

    for (int i = tid; i < 19 * 512; i += 512) wlds[i] = wBg[i];

    unsigned int wrA[180];
#pragma unroll
    for (int m = 0; m < 180; ++m) wrA[m] = wrAg[m * 512 + tid];

    const half_t* zb = zg + (size_t)b * Tv * Hv;
    half_t* rb = rstore + (size_t)b * Tv * Hv;

    float h = h0[tid];
    half_t r0 = (half_t)tanhf(h);
    s_r16[tid] = r0;
    rb[tid] = r0;
    half_t zpf = zb[tid];                    // prefetch z[0]
    __syncthreads();

    int cur = 0;
    for (int t = 0; t < Tv - 1; ++t) {
        half_t zc = zpf;
        zpf = zb[(size_t)(t + 1) * Hv + tid];   // prefetch next (row t=2047 exists, unused)

        const uint4* rq = s_r4 + cur * 64;
        float a0 = 0.f, a1 = 0.f, a2 = 0.f, a3 = 0.f;
#pragma unroll
        for (int q = 0; q < 45; ++q) {           // k in [0,360): register-resident weights
            uint4 rv = rq[q];                    // LDS broadcast (same addr all lanes)
            a0 = fdot2(wrA[4 * q + 0], rv.x, a0);
            a1 = fdot2(wrA[4 * q + 1], rv.y, a1);
            a2 = fdot2(wrA[4 * q + 2], rv.z, a2);
            a3 = fdot2(wrA[4 * q + 3], rv.w, a3);
        }
#pragma unroll
        for (int g = 0; g < 19; ++g) {           // k in [360,512): LDS-resident weights
            uint4 rv = rq[45 + g];
            uint4 wv = wlds[g * 512 + tid];      // consecutive lanes -> conflict-free b128
            a0 = fdot2(wv.x, rv.x, a0);
            a1 = fdot2(wv.y, rv.y, a1);
            a2 = fdot2(wv.z, rv.z, a2);
            a3 = fdot2(wv.w, rv.w, a3);
        }
        float acc = (a0 + a1) + (a2 + a3);
        h = 0.9f * h + 0.1f * acc + (float)zc;
        half_t r = (half_t)tanhf(h);
        s_r16[(cur ^ 1) * 512 + tid] = r;
        rb[(size_t)(t + 1) * Hv + tid] = r;
        __syncthreads();                          // single barrier/step: ping-pong is race-free
        cur ^= 1;
    }
}

// out[bt][o] = sum_j r[bt][j] * wout[j][o]; 32 bt-rows/block, 256 threads.
__global__ __launch_bounds__(256) void out_kernel(
    const half_t* __restrict__ rstore, const uint4* __restrict__ wop4, float* __restrict__ out)
{
    __shared__ uint4 rr[32 * 64];    // 32 KB
    const int tid = threadIdx.x;
    const int o = tid & 63, q = tid >> 6;
    const size_t bt0 = (size_t)blockIdx.x * 32;

    for (int idx = tid; idx < 32 * 64; idx += 256)
        rr[idx] = ((const uint4*)rstore)[bt0 * 64 + idx];
    __syncthreads();

    float acc[8] = {0.f, 0.f, 0.f, 0.f, 0.f, 0.f, 0.f, 0.f};
#pragma unroll 8
    for (int g = 0; g < 64; ++g) {
        uint4 wv = wop4[g * 64 + o];             // L2-resident, coalesced per wave
#pragma unroll
        for (int i = 0; i < 8; ++i) {
            uint4 rv = rr[(q + 4 * i) * 64 + g]; // broadcast within wave
            float a = fdot2(wv.x, rv.x, acc[i]);
            a = fdot2(wv.y, rv.y, a);
            a = fdot2(wv.z, rv.z, a);
            acc[i] = fdot2(wv.w, rv.w, a);
        }
    }
#pragma unroll
    for (int i = 0; i < 8; ++i)
        out[(bt0 + q + 4 * i) * Ov + o] = acc[i];
}

// ===================== LEGACY FALLBACK (R1, proven) =====================
__global__ void pack_wrec_k(const float* __restrict__ wrec, unsigned int* __restrict__ wp) {
    int tid = blockIdx.x * 256 + threadIdx.x;
    int k = tid & 3, j = (tid >> 2) & 511, q = tid >> 11;
    int i0 = 8 * q + 2 * k;
    wp[tid] = pack2(wrec[j * Hv + i0], wrec[j * Hv + i0 + 1]);
}
__global__ void pack_wi_k(const float* __restrict__ wi, unsigned int* __restrict__ wp) {
    int tid = blockIdx.x * 256 + threadIdx.x;
    int k = tid & 3, j = (tid >> 2) & 511, q = tid >> 11;
    int i0 = 8 * q + 2 * k;
    wp[tid] = pack2(wi[i0 * Hv + j], wi[(i0 + 1) * Hv + j]);
}
__global__ void pack_wout_k(const float* __restrict__ wout, unsigned int* __restrict__ wp) {
    int tid = blockIdx.x * 256 + threadIdx.x;
    int o = tid & 63, m = tid >> 6;
    wp[tid] = pack2(wout[(2 * m) * Ov + o], wout[(2 * m + 1) * Ov + o]);
}
__global__ __launch_bounds__(512) void rnn_persistent(
    const float* __restrict__ x, const float* __restrict__ noise,
    const float* __restrict__ h0,
    const unsigned int* __restrict__ wrecp,
    const unsigned int* __restrict__ wip,
    const unsigned int* __restrict__ wop,
    float* __restrict__ out)
{
    __shared__ __align__(16) unsigned int s_r[2][256];
    __shared__ __align__(16) unsigned int s_x[64];
    const int tid = threadIdx.x;
    const int b = blockIdx.x;
    const int o = tid >> 3;
    const int g = tid & 7;
    const float* xb = x + (size_t)b * Tv * Iv;
    const float* nb = noise + (size_t)b * Tv * Hv;
    float* ob = out + (size_t)b * Tv * Ov;
    unsigned int wiReg[64];
#pragma unroll
    for (int m = 0; m < 64; ++m)
        wiReg[m] = wip[(((m >> 2) * Hv) + tid) * 4 + (m & 3)];
    unsigned int wo[32];
#pragma unroll
    for (int k = 0; k < 32; ++k)
        wo[k] = wop[(g * 32 + k) * Ov + o];
    float h = h0[tid];
    ((half_t*)&s_r[0][0])[tid] = (half_t)tanhf(h);
    __syncthreads();
    {
        float po = 0.f;
        const uint4* r2 = (const uint4*)&s_r[0][0];
#pragma unroll
        for (int k = 0; k < 8; ++k) {
            uint4 rv = r2[g * 8 + k];
            po = fdot2(wo[4 * k + 0], rv.x, po);
            po = fdot2(wo[4 * k + 1], rv.y, po);
            po = fdot2(wo[4 * k + 2], rv.z, po);
            po = fdot2(wo[4 * k + 3], rv.w, po);
        }
        po += __shfl_xor(po, 1, 64);
        po += __shfl_xor(po, 2, 64);
        po += __shfl_xor(po, 4, 64);
        if (g == 0) ob[o] = po;
    }
    const uint4* wr4 = (const uint4*)wrecp;
    int cur = 0;
    for (int t = 0; t < Tv - 1; ++t) {
        const int nxt = cur ^ 1;
        float nval = nb[t * Hv + tid];
        if (tid < Iv) ((half_t*)&s_x[0])[tid] = (half_t)xb[t * Iv + tid];
        __syncthreads();
        float acc = 0.f;
        const uint4* rr4 = (const uint4*)&s_r[cur][0];
#pragma unroll 8
        for (int q = 0; q < 64; ++q) {
            uint4 w = wr4[q * Hv + tid];
            uint4 r = rr4[q];
            acc = fdot2(w.x, r.x, acc);
            acc = fdot2(w.y, r.y, acc);
            acc = fdot2(w.z, r.z, acc);
            acc = fdot2(w.w, r.w, acc);
        }
        const uint4* xx4 = (const uint4*)&s_x[0];
#pragma unroll
        for (int m = 0; m < 16; ++m) {
            uint4 xv = xx4[m];
            acc = fdot2(wiReg[4 * m + 0], xv.x, acc);
            acc = fdot2(wiReg[4 * m + 1], xv.y, acc);
            acc = fdot2(wiReg[4 * m + 2], xv.z, acc);
            acc = fdot2(wiReg[4 * m + 3], xv.w, acc);
        }
        h = h + 0.0005f * nval + 0.1f * (acc - h);
        ((half_t*)&s_r[nxt][0])[tid] = (half_t)tanhf(h);
        __syncthreads();
        float po = 0.f;
        const uint4* r2 = (const uint4*)&s_r[nxt][0];
#pragma unroll
        for (int k = 0; k < 8; ++k) {
            uint4 rv = r2[g * 8 + k];
            po = fdot2(wo[4 * k + 0], rv.x, po);
            po = fdot2(wo[4 * k + 1], rv.y, po);
            po = fdot2(wo[4 * k + 2], rv.z, po);
            po = fdot2(wo[4 * k + 3], rv.w, po);
        }
        po += __shfl_xor(po, 1, 64);
        po += __shfl_xor(po, 2, 64);
        po += __shfl_xor(po, 4, 64);
        if (g == 0) ob[(t + 1) * Ov + o] = po;
        cur = nxt;
    }
}

// ===================== LAUNCHER =====================
extern "C" void kernel_launch(void* const* d_in, const int* in_sizes, int n_in,
                              void* d_out, int out_size, void* d_ws, size_t ws_size,
                              hipStream_t stream) {
    const float* input = (const float*)d_in[0];
    const float* noise = (const float*)d_in[1];
    const float* wi    = (const float*)d_in[2];
    const float* wrec  = (const float*)d_in[3];
    const float* wout  = (const float*)d_in[4];
    const float* h0    = (const float*)d_in[5];
    float* out = (float*)d_out;

    const size_t Z_OFF  = 0;                         // z:      64*2048*512*2 = 134217728
    const size_t R_OFF  = Z_OFF + 134217728;         // rstore: 134217728
    const size_t WA_OFF = R_OFF + 134217728;         // wrA:    180*512*4 = 368640
    const size_t WB_OFF = WA_OFF + 368640;           // wB:     19*512*16 = 155648
    const size_t WI_OFF = WB_OFF + 155648;           // wip:    64*512*4 = 131072
    const size_t WO_OFF = WI_OFF + 131072;           // wop4:   64*64*16 = 65536
    const size_t NEED   = WO_OFF + 65536;            // ~256.7 MB

    if (ws_size >= NEED) {
        unsigned char* ws = (unsigned char*)d_ws;
        half_t*       zg    = (half_t*)(ws + Z_OFF);
        half_t*       rsg   = (half_t*)(ws + R_OFF);
        unsigned int* wrAg  = (unsigned int*)(ws + WA_OFF);
        unsigned int* wBg   = (unsigned int*)(ws + WB_OFF);
        unsigned int* wipg  = (unsigned int*)(ws + WI_OFF);
        uint4*        wop4g = (uint4*)(ws + WO_OFF);

        hipLaunchKernelGGL(pack_wrA_k, dim3(360), dim3(256), 0, stream, wrec, wrAg);
        hipLaunchKernelGGL(pack_wB_k,  dim3(152), dim3(256), 0, stream, wrec, wBg);
        hipLaunchKernelGGL(pack_wip_k, dim3(128), dim3(256), 0, stream, wi, wipg);
        hipLaunchKernelGGL(pack_wop_k, dim3(16),  dim3(256), 0, stream, wout, wop4g);

        hipLaunchKernelGGL(z_kernel, dim3((Bv * Tv) / 32), dim3(512), 0, stream,
                           input, noise, wipg, zg);

        const int smem = 19 * 512 * 16 + 2 * 512 * 2;   // 157696 B
        hipFuncSetAttribute((const void*)rnn_fast,
                            hipFuncAttributeMaxDynamicSharedMemorySize, smem);
        hipLaunchKernelGGL(rnn_fast, dim3(Bv), dim3(512), smem, stream,
                           wrAg, (const uint4*)wBg, zg, h0, rsg);

        hipLaunchKernelGGL(out_kernel, dim3((Bv * Tv) / 32), dim3(256), 0, stream,
                           rsg, wop4g, out);
    } else {
        unsigned int* wrecp = (unsigned int*)d_ws;
        unsigned int* wip   = wrecp + 64 * 512 * 4;
        unsigned int* wop   = wip   + 16 * 512 * 4;
        hipLaunchKernelGGL(pack_wrec_k, dim3(512), dim3(256), 0, stream, wrec, wrecp);
        hipLaunchKernelGGL(pack_wi_k,   dim3(128), dim3(256), 0, stream, wi, wip);
        hipLaunchKernelGGL(pack_wout_k, dim3(64),  dim3(256), 0, stream, wout, wop);
        hipLaunchKernelGGL(rnn_persistent, dim3(Bv), dim3(512), 0, stream,
                           input, noise, h0, wrecp, wip, wop, out);
    }
}

// Round 3
// 3577.817 us; speedup vs baseline: 4.9943x; 1.0018x over previous
//
#include <hip/hip_runtime.h>
#include <stdint.h>

#define Bv 64
#define Tv 2048
#define Iv 128
#define Hv 512
#define Ov 64

typedef _Float16 half_t;
typedef _Float16 half2_t __attribute__((ext_vector_type(2)));

__device__ __forceinline__ float fdot2(unsigned int a, unsigned int b, float c) {
#if __has_builtin(__builtin_amdgcn_fdot2)
    return __builtin_amdgcn_fdot2(__builtin_bit_cast(half2_t, a),
                                  __builtin_bit_cast(half2_t, b), c, false);
#else
    half2_t ha = __builtin_bit_cast(half2_t, a);
    half2_t hb = __builtin_bit_cast(half2_t, b);
    return c + (float)ha.x * (float)hb.x + (float)ha.y * (float)hb.y;
#endif
}

__device__ __forceinline__ unsigned int pack2(float a, float b) {
    half2_t v; v.x = (half_t)a; v.y = (half_t)b;
    return __builtin_bit_cast(unsigned int, v);
}

// ===================== FAST PATH =====================
// wrec row k-range split: [0,360) -> registers (180 uints), [360,512) -> LDS (19 uint4)

// wrA[m][j] (m<180, j<512): half2(wrec[j][2m], wrec[j][2m+1])
__global__ void pack_wrA_k(const float* __restrict__ wrec, unsigned int* __restrict__ wp) {
    int idx = blockIdx.x * 256 + threadIdx.x;
    if (idx >= 180 * 512) return;
    int j = idx & 511, m = idx >> 9;
    wp[idx] = pack2(wrec[j * Hv + 2 * m], wrec[j * Hv + 2 * m + 1]);
}

// wB[g][j][c] (g<19, j<512, c<4): half2(wrec[j][360+8g+2c], wrec[j][360+8g+2c+1])
__global__ void pack_wB_k(const float* __restrict__ wrec, unsigned int* __restrict__ wp) {
    int idx = blockIdx.x * 256 + threadIdx.x;
    if (idx >= 19 * 512 * 4) return;
    int c = idx & 3, j = (idx >> 2) & 511, g = idx >> 11;
    int k = 360 + 8 * g + 2 * c;
    wp[idx] = pack2(wrec[j * Hv + k], wrec[j * Hv + k + 1]);
}

// wip[m][j] (m<64, j<512): half2(wi[2m][j], wi[2m+1][j])
__global__ void pack_wip_k(const float* __restrict__ wi, unsigned int* __restrict__ wp) {
    int idx = blockIdx.x * 256 + threadIdx.x;
    int j = idx & 511, m = idx >> 9;
    wp[idx] = pack2(wi[(2 * m) * Hv + j], wi[(2 * m + 1) * Hv + j]);
}

// wop4[g][o] (g<64, o<64): uint4 of half2 pairs of wout rows 8g..8g+7, col o
__global__ void pack_wop_k(const float* __restrict__ wout, uint4* __restrict__ wp) {
    int idx = blockIdx.x * 256 + threadIdx.x;
    if (idx >= 64 * 64) return;
    int o = idx & 63, g = idx >> 6;
    uint4 v;
    v.x = pack2(wout[(8 * g + 0) * Ov + o], wout[(8 * g + 1) * Ov + o]);
    v.y = pack2(wout[(8 * g + 2) * Ov + o], wout[(8 * g + 3) * Ov + o]);
    v.z = pack2(wout[(8 * g + 4) * Ov + o], wout[(8 * g + 5) * Ov + o]);
    v.w = pack2(wout[(8 * g + 6) * Ov + o], wout[(8 * g + 7) * Ov + o]);
    wp[idx] = v;
}

// z[bt][j] = 0.1 * sum_i x[bt][i]*wi[i][j] + 0.0005 * noise[bt][j], f16.
__global__ __launch_bounds__(512) void z_kernel(
    const float* __restrict__ x, const float* __restrict__ noise,
    const unsigned int* __restrict__ wip, half_t* __restrict__ zg)
{
    __shared__ uint4 xs[32 * 16];
    const int tid = threadIdx.x;
    const size_t bt0 = (size_t)blockIdx.x * 32;

    unsigned int wiR[64];
#pragma unroll
    for (int m = 0; m < 64; ++m) wiR[m] = wip[m * 512 + tid];

    for (int idx = tid; idx < 32 * 64; idx += 512) {
        int row = idx >> 6, m = idx & 63;
        float2 xv = ((const float2*)x)[(bt0 + row) * 64 + m];
        ((unsigned int*)xs)[idx] = pack2(xv.x, xv.y);
    }
    __syncthreads();

    for (int row = 0; row < 32; ++row) {
        float a0 = 0.f, a1 = 0.f, a2 = 0.f, a3 = 0.f;
#pragma unroll
        for (int g = 0; g < 16; ++g) {
            uint4 xv = xs[row * 16 + g];
            a0 = fdot2(wiR[4 * g + 0], xv.x, a0);
            a1 = fdot2(wiR[4 * g + 1], xv.y, a1);
            a2 = fdot2(wiR[4 * g + 2], xv.z, a2);
            a3 = fdot2(wiR[4 * g + 3], xv.w, a3);
        }
        float nv = noise[(bt0 + row) * 512 + tid];
        zg[(bt0 + row) * 512 + tid] = (half_t)(0.1f * ((a0 + a1) + (a2 + a3)) + 0.0005f * nv);
    }
}

// Persistent scan: 1 WG/batch, 512 threads, wrec in regs+LDS, r via LDS ping-pong.
// amdgpu_waves_per_eu(2,2): occupancy is LDS-capped at 2 waves/SIMD anyway (157KB
// dynamic LDS, 1 WG/CU); pin it so the allocator may use up to 256 VGPRs and has
// no occupancy incentive to spill wrA[180] to scratch (R2: VGPR_Count=112 = spill).
__global__ __launch_bounds__(512) __attribute__((amdgpu_waves_per_eu(2, 2)))
void rnn_fast(
    const unsigned int* __restrict__ wrAg,   // [180][512]
    const uint4* __restrict__ wBg,           // [19][512]
    const half_t* __restrict__ zg,           // [B][T][512]
    const float* __restrict__ h0,
    half_t* __restrict__ rstore)             // [B][T][512]
{
    extern __shared__ unsigned char smem[];
    uint4* wlds = (uint4*)smem;                                   // 155648 B
    half_t* s_r16 = (half_t*)(smem + 19 * 512 * 16);              // [2][512] f16
    const uint4* s_r4 = (const uint4*)s_r16;

    const int tid = threadIdx.x;
    const int b = blockIdx.x;

    for (int i = tid; i < 19 * 512; i += 512) wlds[i] = wBg[i];

    unsigned int wrA[180];
#pragma unroll
    for (int m = 0; m < 180; ++m) wrA[m] = wrAg[m * 512 + tid];

    const half_t* zb = zg + (size_t)b * Tv * Hv;
    half_t* rb = rstore + (size_t)b * Tv * Hv;

    float h = h0[tid];
    half_t r0 = (half_t)tanhf(h);
    s_r16[tid] = r0;
    rb[tid] = r0;
    half_t zpf = zb[tid];
    __syncthreads();

    int cur = 0;
    for (int t = 0; t < Tv - 1; ++t) {
        half_t zc = zpf;
        zpf = zb[(size_t)(t + 1) * Hv + tid];

        const uint4* rq = s_r4 + cur * 64;
        float a0 = 0.f, a1 = 0.f, a2 = 0.f, a3 = 0.f;
#pragma unroll
        for (int q = 0; q < 45; ++q) {           // k in [0,360): register weights
            uint4 rv = rq[q];                    // LDS broadcast
            a0 = fdot2(wrA[4 * q + 0], rv.x, a0);
            a1 = fdot2(wrA[4 * q + 1], rv.y, a1);
            a2 = fdot2(wrA[4 * q + 2], rv.z, a2);
            a3 = fdot2(wrA[4 * q + 3], rv.w, a3);
        }
#pragma unroll
        for (int g = 0; g < 19; ++g) {           // k in [360,512): LDS weights
            uint4 rv = rq[45 + g];
            uint4 wv = wlds[g * 512 + tid];
            a0 = fdot2(wv.x, rv.x, a0);
            a1 = fdot2(wv.y, rv.y, a1);
            a2 = fdot2(wv.z, rv.z, a2);
            a3 = fdot2(wv.w, rv.w, a3);
        }
        float acc = (a0 + a1) + (a2 + a3);
        h = 0.9f * h + 0.1f * acc + (float)zc;
        half_t r = (half_t)tanhf(h);
        s_r16[(cur ^ 1) * 512 + tid] = r;
        rb[(size_t)(t + 1) * Hv + tid] = r;
        __syncthreads();
        cur ^= 1;
    }
}

// out[bt][o] = sum_j r[bt][j] * wout[j][o]
__global__ __launch_bounds__(256) void out_kernel(
    const half_t* __restrict__ rstore, const uint4* __restrict__ wop4, float* __restrict__ out)
{
    __shared__ uint4 rr[32 * 64];
    const int tid = threadIdx.x;
    const int o = tid & 63, q = tid >> 6;
    const size_t bt0 = (size_t)blockIdx.x * 32;

    for (int idx = tid; idx < 32 * 64; idx += 256)
        rr[idx] = ((const uint4*)rstore)[bt0 * 64 + idx];
    __syncthreads();

    float acc[8] = {0.f, 0.f, 0.f, 0.f, 0.f, 0.f, 0.f, 0.f};
#pragma unroll 8
    for (int g = 0; g < 64; ++g) {
        uint4 wv = wop4[g * 64 + o];
#pragma unroll
        for (int i = 0; i < 8; ++i) {
            uint4 rv = rr[(q + 4 * i) * 64 + g];
            float a = fdot2(wv.x, rv.x, acc[i]);
            a = fdot2(wv.y, rv.y, a);
            a = fdot2(wv.z, rv.z, a);
            acc[i] = fdot2(wv.w, rv.w, a);
        }
    }
#pragma unroll
    for (int i = 0; i < 8; ++i)
        out[(bt0 + q + 4 * i) * Ov + o] = acc[i];
}

// ===================== LEGACY FALLBACK (R1, proven) =====================
__global__ void pack_wrec_k(const float* __restrict__ wrec, unsigned int* __restrict__ wp) {
    int tid = blockIdx.x * 256 + threadIdx.x;
    int k = tid & 3, j = (tid >> 2) & 511, q = tid >> 11;
    int i0 = 8 * q + 2 * k;
    wp[tid] = pack2(wrec[j * Hv + i0], wrec[j * Hv + i0 + 1]);
}
__global__ void pack_wi_k(const float* __restrict__ wi, unsigned int* __restrict__ wp) {
    int tid = blockIdx.x * 256 + threadIdx.x;
    int k = tid & 3, j = (tid >> 2) & 511, q = tid >> 11;
    int i0 = 8 * q + 2 * k;
    wp[tid] = pack2(wi[i0 * Hv + j], wi[(i0 + 1) * Hv + j]);
}
__global__ void pack_wout_k(const float* __restrict__ wout, unsigned int* __restrict__ wp) {
    int tid = blockIdx.x * 256 + threadIdx.x;
    int o = tid & 63, m = tid >> 6;
    wp[tid] = pack2(wout[(2 * m) * Ov + o], wout[(2 * m + 1) * Ov + o]);
}
__global__ __launch_bounds__(512) void rnn_persistent(
    const float* __restrict__ x, const float* __restrict__ noise,
    const float* __restrict__ h0,
    const unsigned int* __restrict__ wrecp,
    const unsigned int* __restrict__ wip,
    const unsigned int* __restrict__ wop,
    float* __restrict__ out)
{
    __shared__ __align__(16) unsigned int s_r[2][256];
    __shared__ __align__(16) unsigned int s_x[64];
    const int tid = threadIdx.x;
    const int b = blockIdx.x;
    const int o = tid >> 3;
    const int g = tid & 7;
    const float* xb = x + (size_t)b * Tv * Iv;
    const float* nb = noise + (size_t)b * Tv * Hv;
    float* ob = out + (size_t)b * Tv * Ov;
    unsigned int wiReg[64];
#pragma unroll
    for (int m = 0; m < 64; ++m)
        wiReg[m] = wip[(((m >> 2) * Hv) + tid) * 4 + (m & 3)];
    unsigned int wo[32];
#pragma unroll
    for (int k = 0; k < 32; ++k)
        wo[k] = wop[(g * 32 + k) * Ov + o];
    float h = h0[tid];
    ((half_t*)&s_r[0][0])[tid] = (half_t)tanhf(h);
    __syncthreads();
    {
        float po = 0.f;
        const uint4* r2 = (const uint4*)&s_r[0][0];
#pragma unroll
        for (int k = 0; k < 8; ++k) {
            uint4 rv = r2[g * 8 + k];
            po = fdot2(wo[4 * k + 0], rv.x, po);
            po = fdot2(wo[4 * k + 1], rv.y, po);
            po = fdot2(wo[4 * k + 2], rv.z, po);
            po = fdot2(wo[4 * k + 3], rv.w, po);
        }
        po += __shfl_xor(po, 1, 64);
        po += __shfl_xor(po, 2, 64);
        po += __shfl_xor(po, 4, 64);
        if (g == 0) ob[o] = po;
    }
    const uint4* wr4 = (const uint4*)wrecp;
    int cur = 0;
    for (int t = 0; t < Tv - 1; ++t) {
        const int nxt = cur ^ 1;
        float nval = nb[t * Hv + tid];
        if (tid < Iv) ((half_t*)&s_x[0])[tid] = (half_t)xb[t * Iv + tid];
        __syncthreads();
        float acc = 0.f;
        const uint4* rr4 = (const uint4*)&s_r[cur][0];
#pragma unroll 8
        for (int q = 0; q < 64; ++q) {
            uint4 w = wr4[q * Hv + tid];
            uint4 r = rr4[q];
            acc = fdot2(w.x, r.x, acc);
            acc = fdot2(w.y, r.y, acc);
            acc = fdot2(w.z, r.z, acc);
            acc = fdot2(w.w, r.w, acc);
        }
        const uint4* xx4 = (const uint4*)&s_x[0];
#pragma unroll
        for (int m = 0; m < 16; ++m) {
            uint4 xv = xx4[m];
            acc = fdot2(wiReg[4 * m + 0], xv.x, acc);
            acc = fdot2(wiReg[4 * m + 1], xv.y, acc);
            acc = fdot2(wiReg[4 * m + 2], xv.z, acc);
            acc = fdot2(wiReg[4 * m + 3], xv.w, acc);
        }
        h = h + 0.0005f * nval + 0.1f * (acc - h);
        ((half_t*)&s_r[nxt][0])[tid] = (half_t)tanhf(h);
        __syncthreads();
        float po = 0.f;
        const uint4* r2 = (const uint4*)&s_r[nxt][0];
#pragma unroll
        for (int k = 0; k < 8; ++k) {
            uint4 rv = r2[g * 8 + k];
            po = fdot2(wo[4 * k + 0], rv.x, po);
            po = fdot2(wo[4 * k + 1], rv.y, po);
            po = fdot2(wo[4 * k + 2], rv.z, po);
            po = fdot2(wo[4 * k + 3], rv.w, po);
        }
        po += __shfl_xor(po, 1, 64);
        po += __shfl_xor(po, 2, 64);
        po += __shfl_xor(po, 4, 64);
        if (g == 0) ob[(t + 1) * Ov + o] = po;
        cur = nxt;
    }
}

// ===================== LAUNCHER =====================
extern "C" void kernel_launch(void* const* d_in, const int* in_sizes, int n_in,
                              void* d_out, int out_size, void* d_ws, size_t ws_size,
                              hipStream_t stream) {
    const float* input = (const float*)d_in[0];
    const float* noise = (const float*)d_in[1];
    const float* wi    = (const float*)d_in[2];
    const float* wrec  = (const float*)d_in[3];
    const float* wout  = (const float*)d_in[4];
    const float* h0    = (const float*)d_in[5];
    float* out = (float*)d_out;

    const size_t Z_OFF  = 0;
    const size_t R_OFF  = Z_OFF + 134217728;
    const size_t WA_OFF = R_OFF + 134217728;
    const size_t WB_OFF = WA_OFF + 368640;
    const size_t WI_OFF = WB_OFF + 155648;
    const size_t WO_OFF = WI_OFF + 131072;
    const size_t NEED   = WO_OFF + 65536;

    if (ws_size >= NEED) {
        unsigned char* ws = (unsigned char*)d_ws;
        half_t*       zg    = (half_t*)(ws + Z_OFF);
        half_t*       rsg   = (half_t*)(ws + R_OFF);
        unsigned int* wrAg  = (unsigned int*)(ws + WA_OFF);
        unsigned int* wBg   = (unsigned int*)(ws + WB_OFF);
        unsigned int* wipg  = (unsigned int*)(ws + WI_OFF);
        uint4*        wop4g = (uint4*)(ws + WO_OFF);

        hipLaunchKernelGGL(pack_wrA_k, dim3(360), dim3(256), 0, stream, wrec, wrAg);
        hipLaunchKernelGGL(pack_wB_k,  dim3(152), dim3(256), 0, stream, wrec, wBg);
        hipLaunchKernelGGL(pack_wip_k, dim3(128), dim3(256), 0, stream, wi, wipg);
        hipLaunchKernelGGL(pack_wop_k, dim3(16),  dim3(256), 0, stream, wout, wop4g);

        hipLaunchKernelGGL(z_kernel, dim3((Bv * Tv) / 32), dim3(512), 0, stream,
                           input, noise, wipg, zg);

        const int smem = 19 * 512 * 16 + 2 * 512 * 2;   // 157696 B
        hipFuncSetAttribute((const void*)rnn_fast,
                            hipFuncAttributeMaxDynamicSharedMemorySize, smem);
        hipLaunchKernelGGL(rnn_fast, dim3(Bv), dim3(512), smem, stream,
                           wrAg, (const uint4*)wBg, zg, h0, rsg);

        hipLaunchKernelGGL(out_kernel, dim3((Bv * Tv) / 32), dim3(256), 0, stream,
                           rsg, wop4g, out);
    } else {
        unsigned int* wrecp = (unsigned int*)d_ws;
        unsigned int* wip   = wrecp + 64 * 512 * 4;
        unsigned int* wop   = wip   + 16 * 512 * 4;
        hipLaunchKernelGGL(pack_wrec_k, dim3(512), dim3(256), 0, stream, wrec, wrecp);
        hipLaunchKernelGGL(pack_wi_k,   dim3(128), dim3(256), 0, stream, wi, wip);
        hipLaunchKernelGGL(pack_wout_k, dim3(64),  dim3(256), 0, stream, wout, wop);
        hipLaunchKernelGGL(rnn_persistent, dim3(Bv), dim3(512), 0, stream,
                           input, noise, h0, wrecp, wip, wop, out);
    }
}